// Round 3
// baseline (211.497 us; speedup 1.0000x reference)
//
#include <hip/hip_runtime.h>
#include <hip/hip_bf16.h>
#include <cstdint>
#include <cstddef>

#define CIN   512
#define COUT  512
#define LLEN  2048
#define BATCH 8
#define KTAP  8
#define LPAD  (LLEN + 8)   // 8 zero halo rows at the front of each batch

typedef __bf16 bf16x8_t __attribute__((ext_vector_type(8)));
typedef float  f32x4_t  __attribute__((ext_vector_type(4)));
typedef unsigned short u16x8_t __attribute__((ext_vector_type(8)));

__device__ __forceinline__ unsigned short f2bf(float f) {
  __bf16 h = (__bf16)f;                       // RNE fptrunc
  return __builtin_bit_cast(unsigned short, h);
}

__device__ __forceinline__ void gl2lds16(unsigned short* lds, const unsigned short* g) {
  __builtin_amdgcn_global_load_lds(
      (const __attribute__((address_space(1))) unsigned int*)g,
      (__attribute__((address_space(3))) unsigned int*)lds,
      16, 0, 0);
}

// ---------------- fused pre-pass ----------------
// blocks [0, 2048): x (B,CIN,L) fp32 -> xtp (B, 8+L, CIN) bf16 transpose+cast
//                   (l0==0 blocks also zero the 8-row halo)
// blocks [2048, 3072): W (COUT*K, CIN) fp32 -> bf16 Wb, 8 elems/thread
__global__ __launch_bounds__(256) void prepass_kernel(
    const float* __restrict__ x, unsigned short* __restrict__ xtp,
    const float4* __restrict__ W, u16x8_t* __restrict__ Wb) {
  const int bid = blockIdx.x;
  const int t   = threadIdx.x;

  if (bid >= 2048) {                   // ---- W convert ----
    int idx = (bid - 2048) * 256 + t;  // 262144 threads, 8 elems each
    float4 a = W[idx * 2], b = W[idx * 2 + 1];
    u16x8_t o;
    o[0] = f2bf(a.x); o[1] = f2bf(a.y); o[2] = f2bf(a.z); o[3] = f2bf(a.w);
    o[4] = f2bf(b.x); o[5] = f2bf(b.y); o[6] = f2bf(b.z); o[7] = f2bf(b.w);
    Wb[idx] = o;
    return;
  }

  // ---- x transpose: 64(c) x 64(l) tile ----
  __shared__ float tile[64][65];
  const int b  = bid >> 8;             // 0..7
  const int c0 = ((bid >> 5) & 7) * 64;
  const int l0 = (bid & 31) * 64;

  if ((bid & 31) == 0 && t < 64) {     // halo zero: rows 0..7, cols c0..c0+63
    unsigned short* hp = xtp + ((size_t)b * LPAD + (t >> 3)) * CIN + c0 + (t & 7) * 8;
    *(u16x8_t*)hp = (u16x8_t){0, 0, 0, 0, 0, 0, 0, 0};
  }

  {
    const int cr = t >> 2;             // 0..63
    const int lv = (t & 3) * 16;       // 0,16,32,48
    const float* src = x + ((size_t)b * CIN + c0 + cr) * LLEN + l0 + lv;
#pragma unroll
    for (int i = 0; i < 4; ++i) {
      float4 v = *(const float4*)(src + 4 * i);
      tile[cr][lv + 4 * i + 0] = v.x;
      tile[cr][lv + 4 * i + 1] = v.y;
      tile[cr][lv + 4 * i + 2] = v.z;
      tile[cr][lv + 4 * i + 3] = v.w;
    }
  }
  __syncthreads();
  {
    const int l    = t >> 2;           // 0..63
    const int cseg = (t & 3) * 16;     // 0,16,32,48
    unsigned short ov[16];
#pragma unroll
    for (int u = 0; u < 16; ++u) ov[u] = f2bf(tile[cseg + u][l]);
    unsigned short* dst = xtp + ((size_t)b * LPAD + 8 + l0 + l) * CIN + c0 + cseg;
    *(u16x8_t*)dst       = *(const u16x8_t*)&ov[0];
    *(u16x8_t*)(dst + 8) = *(const u16x8_t*)&ov[8];
  }
}

// ---------------- fused conv GEMM (A from global/L2, B via LDS) ----------------
// C[o][l] (128x128) = sum_k sum_c W[k*COUT+o][c] * xT[l-k][c] ; bias in epilogue.
// B staged per 64-deep c-tile with 8-row halo (reused by all 8 taps).
// A fragments read straight from Wb (4 MB, L2-resident) as per-lane
// global_load_dwordx4 — no LDS, no barriers in the tap loop, so next-tap A
// prefetch stays in flight across MFMA (fine-grained vmcnt, AITER-style).

__global__ __launch_bounds__(256) void conv_gemm_kernel(
    const unsigned short* __restrict__ Wb,   // (K*COUT, CIN) bf16
    const unsigned short* __restrict__ xtp,  // (B, LPAD, CIN) bf16
    const float* __restrict__ bias,          // (COUT)
    float* __restrict__ y)                   // (B, COUT, LLEN) fp32
{
  __shared__ __align__(16) unsigned short Bs[136 * 64];  // 17 KB (halo)

  const int t    = threadIdx.x;
  const int lane = t & 63;
  const int wid  = t >> 6;
  const int wm   = wid & 1, wn = wid >> 1;
  const int l0   = blockIdx.x * 128;
  const int o0   = blockIdx.y * 128;
  const int b    = blockIdx.z;

  const int quad = lane >> 4;
  const int lrow = lane & 15;

  f32x4_t acc[4][4];
#pragma unroll
  for (int i = 0; i < 4; ++i)
#pragma unroll
    for (int j = 0; j < 4; ++j)
      acc[i][j] = (f32x4_t){0.f, 0.f, 0.f, 0.f};

  // B staging: rows of 64 bf16 = 8 chunks of 16 B; LDS slot s of row r holds
  // source chunk s ^ (r & 7) (swizzle applied on the SOURCE address).
  const int srow    = t >> 3;
  const int schunk  = (t & 7) ^ (srow & 7);
  const int lds_off = t * 8;

  const unsigned short* xb = xtp + (size_t)b * LPAD * CIN;

  // A fragment base for this lane: row = wm*64 + i*16 + lrow, chunk = quad
  const unsigned short* aW =
      Wb + ((size_t)o0 + wm * 64 + lrow) * CIN + quad * 8;
  // addr(kk, h, i) = aW + (kk&7)*COUT*CIN + i*16*CIN + (kk>>3)*64 + h*32

  bf16x8_t afc[2][4], afn[2][4];
#pragma unroll
  for (int h = 0; h < 2; ++h)
#pragma unroll
    for (int i = 0; i < 4; ++i)
      afc[h][i] = *(const bf16x8_t*)(aW + h * 32 + i * 16 * CIN);

#pragma unroll 1
  for (int ct = 0; ct < 8; ++ct) {
    const int c0 = ct * 64;
    if (ct) __syncthreads();           // guard Bs overwrite
    {
      const unsigned short* src = xb + (size_t)(l0 + srow) * CIN + c0 + schunk * 8;
#pragma unroll
      for (int rd = 0; rd < 4; ++rd)
        gl2lds16(Bs + lds_off + rd * 2048, src + (size_t)rd * 32 * CIN);
      if (t < 64) {
        const int r2  = 128 + (t >> 3);
        const int ch2 = (t & 7) ^ (r2 & 7);
        gl2lds16(Bs + 128 * 64 + t * 8,
                 xb + (size_t)(l0 + r2) * CIN + c0 + ch2 * 8);
      }
    }
    __syncthreads();                   // B staging complete

#pragma unroll
    for (int k = 0; k < 8; ++k) {
      const int kk = ct * 8 + k;
      const int kn = (kk + 1 < 64) ? kk + 1 : kk;   // clamp at end
      const unsigned short* an =
          aW + (size_t)(kn & 7) * COUT * CIN + (kn >> 3) * 64;
      // prefetch next tap's A fragments (in flight across this tap's MFMAs)
#pragma unroll
      for (int h = 0; h < 2; ++h)
#pragma unroll
        for (int i = 0; i < 4; ++i)
          afn[h][i] = *(const bf16x8_t*)(an + h * 32 + i * 16 * CIN);

#pragma unroll
      for (int h = 0; h < 2; ++h) {
        bf16x8_t bfr[4];
#pragma unroll
        for (int j = 0; j < 4; ++j) {
          int row  = (8 - k) + wn * 64 + j * 16 + lrow;   // halo shift
          int slot = (h * 4 + quad) ^ (row & 7);
          bfr[j] = *(const bf16x8_t*)(Bs + row * 64 + slot * 8);
        }
#pragma unroll
        for (int i = 0; i < 4; ++i)
#pragma unroll
          for (int j = 0; j < 4; ++j)
            acc[i][j] = __builtin_amdgcn_mfma_f32_16x16x32_bf16(afc[h][i], bfr[j], acc[i][j], 0, 0, 0);
      }
#pragma unroll
      for (int h = 0; h < 2; ++h)
#pragma unroll
        for (int i = 0; i < 4; ++i)
          afc[h][i] = afn[h][i];
    }
  }

  // epilogue: D layout col = lane&15 (=l), row = quad*4+reg (=o)
#pragma unroll
  for (int i = 0; i < 4; ++i) {
    const int o_base = o0 + wm * 64 + i * 16 + quad * 4;
    const float4 bv = *(const float4*)(bias + o_base);
    const float bvr[4] = {bv.x, bv.y, bv.z, bv.w};
#pragma unroll
    for (int j = 0; j < 4; ++j) {
      const int l = l0 + wn * 64 + j * 16 + lrow;
#pragma unroll
      for (int r = 0; r < 4; ++r) {
        y[((size_t)b * COUT + o_base + r) * LLEN + l] = acc[i][j][r] + bvr[r];
      }
    }
  }
}

// ---------------- launch ----------------

extern "C" void kernel_launch(void* const* d_in, const int* in_sizes, int n_in,
                              void* d_out, int out_size, void* d_ws, size_t ws_size,
                              hipStream_t stream) {
  const float* x    = (const float*)d_in[0];   // (8, 512, 2048)
  const float* W    = (const float*)d_in[1];   // (4096, 512)
  const float* bias = (const float*)d_in[2];   // (512)
  float* y          = (float*)d_out;           // (8, 512, 2048)

  unsigned short* xtp = (unsigned short*)d_ws;                     // 16,842,752 B
  unsigned short* Wb  = (unsigned short*)((char*)d_ws +
                        (size_t)BATCH * LPAD * CIN * sizeof(unsigned short));

  prepass_kernel<<<2048 + 1024, 256, 0, stream>>>(
      x, xtp, (const float4*)W, (u16x8_t*)Wb);
  conv_gemm_kernel<<<dim3(LLEN / 128, COUT / 128, BATCH), 256, 0, stream>>>(
      Wb, xtp, bias, y);
}

// Round 4
// 149.900 us; speedup vs baseline: 1.4109x; 1.4109x over previous
//
#include <hip/hip_runtime.h>
#include <hip/hip_bf16.h>
#include <cstdint>
#include <cstddef>

#define CIN   512
#define COUT  512
#define LLEN  2048
#define BATCH 8
#define KTAP  8
#define LPAD  (LLEN + 8)   // 8 zero halo rows at the front of each batch

typedef __bf16 bf16x8_t __attribute__((ext_vector_type(8)));
typedef float  f32x4_t  __attribute__((ext_vector_type(4)));
typedef unsigned short u16x8_t __attribute__((ext_vector_type(8)));

__device__ __forceinline__ unsigned short f2bf(float f) {
  __bf16 h = (__bf16)f;                       // RNE fptrunc
  return __builtin_bit_cast(unsigned short, h);
}

__device__ __forceinline__ void gl2lds16(unsigned short* lds, const unsigned short* g) {
  __builtin_amdgcn_global_load_lds(
      (const __attribute__((address_space(1))) unsigned int*)g,
      (__attribute__((address_space(3))) unsigned int*)lds,
      16, 0, 0);
}

// ---------------- fused pre-pass ----------------
// blocks [0, 2048): x (B,CIN,L) fp32 -> xtp (B, 8+L, CIN) bf16 transpose+cast
//                   (l0==0 blocks also zero the 8-row halo)
// blocks [2048, 3072): W (COUT*K, CIN) fp32 -> bf16 Wb, 8 elems/thread
__global__ __launch_bounds__(256) void prepass_kernel(
    const float* __restrict__ x, unsigned short* __restrict__ xtp,
    const float4* __restrict__ W, u16x8_t* __restrict__ Wb) {
  const int bid = blockIdx.x;
  const int t   = threadIdx.x;

  if (bid >= 2048) {                   // ---- W convert ----
    int idx = (bid - 2048) * 256 + t;  // 262144 threads, 8 elems each
    float4 a = W[idx * 2], b = W[idx * 2 + 1];
    u16x8_t o;
    o[0] = f2bf(a.x); o[1] = f2bf(a.y); o[2] = f2bf(a.z); o[3] = f2bf(a.w);
    o[4] = f2bf(b.x); o[5] = f2bf(b.y); o[6] = f2bf(b.z); o[7] = f2bf(b.w);
    Wb[idx] = o;
    return;
  }

  // ---- x transpose: 64(c) x 64(l) tile ----
  __shared__ float tile[64][65];
  const int b  = bid >> 8;             // 0..7
  const int c0 = ((bid >> 5) & 7) * 64;
  const int l0 = (bid & 31) * 64;

  if ((bid & 31) == 0 && t < 64) {     // halo zero: rows 0..7, cols c0..c0+63
    unsigned short* hp = xtp + ((size_t)b * LPAD + (t >> 3)) * CIN + c0 + (t & 7) * 8;
    *(u16x8_t*)hp = (u16x8_t){0, 0, 0, 0, 0, 0, 0, 0};
  }

  {
    const int cr = t >> 2;             // 0..63
    const int lv = (t & 3) * 16;       // 0,16,32,48
    const float* src = x + ((size_t)b * CIN + c0 + cr) * LLEN + l0 + lv;
#pragma unroll
    for (int i = 0; i < 4; ++i) {
      float4 v = *(const float4*)(src + 4 * i);
      tile[cr][lv + 4 * i + 0] = v.x;
      tile[cr][lv + 4 * i + 1] = v.y;
      tile[cr][lv + 4 * i + 2] = v.z;
      tile[cr][lv + 4 * i + 3] = v.w;
    }
  }
  __syncthreads();
  {
    const int l    = t >> 2;           // 0..63
    const int cseg = (t & 3) * 16;     // 0,16,32,48
    unsigned short ov[16];
#pragma unroll
    for (int u = 0; u < 16; ++u) ov[u] = f2bf(tile[cseg + u][l]);
    unsigned short* dst = xtp + ((size_t)b * LPAD + 8 + l0 + l) * CIN + c0 + cseg;
    *(u16x8_t*)dst       = *(const u16x8_t*)&ov[0];
    *(u16x8_t*)(dst + 8) = *(const u16x8_t*)&ov[8];
  }
}

// ---------------- fused conv GEMM (double-buffered, 1 barrier/tap) ----------------
// C[o][l] (128x128) = sum_k sum_c W[k*COUT+o][c] * xT[l-k][c] ; bias in epilogue.
// As[2]/Bs[2] double buffers: tap kk+1's A staging (and ct+1's B staging on
// tap 7) is issued at the START of tap kk's phase, so the single barrier's
// vmcnt drain is free and ds_reads/MFMAs overlap inside the barrier-free span.

__global__ __launch_bounds__(256) void conv_gemm_kernel(
    const unsigned short* __restrict__ Wb,   // (K*COUT, CIN) bf16
    const unsigned short* __restrict__ xtp,  // (B, LPAD, CIN) bf16
    const float* __restrict__ bias,          // (COUT)
    float* __restrict__ y)                   // (B, COUT, LLEN) fp32
{
  __shared__ __align__(16) unsigned short As[2][128 * 64];  // 2 x 16 KB
  __shared__ __align__(16) unsigned short Bs[2][136 * 64];  // 2 x 17 KB (halo)

  const int t    = threadIdx.x;
  const int lane = t & 63;
  const int wid  = t >> 6;
  const int wm   = wid & 1, wn = wid >> 1;
  const int l0   = blockIdx.x * 128;
  const int o0   = blockIdx.y * 128;
  const int b    = blockIdx.z;

  const int quad = lane >> 4;
  const int lrow = lane & 15;

  f32x4_t acc[4][4];
#pragma unroll
  for (int i = 0; i < 4; ++i)
#pragma unroll
    for (int j = 0; j < 4; ++j)
      acc[i][j] = (f32x4_t){0.f, 0.f, 0.f, 0.f};

  // staging: rows of 64 bf16 = 8 chunks of 16 B; LDS slot s of row r holds
  // source chunk s ^ (r & 7) (swizzle applied on the SOURCE address).
  const int srow    = t >> 3;                       // 0..31 per round
  const int schunk  = (t & 7) ^ (srow & 7);         // swizzled source chunk
  const int lds_off = t * 8;                        // elements (t*16 bytes)

  const unsigned short* xb = xtp + (size_t)b * LPAD * CIN;

  auto stage_A = [&](int kk, int buf) {
    const unsigned short* asrc =
        Wb + (size_t)((kk & 7) * COUT + o0 + srow) * CIN + (kk >> 3) * 64 + schunk * 8;
#pragma unroll
    for (int rd = 0; rd < 4; ++rd)
      gl2lds16(&As[buf][0] + lds_off + rd * 2048, asrc + (size_t)rd * 32 * CIN);
  };
  auto stage_B = [&](int ct, int buf) {
    const int c0 = ct * 64;
    const unsigned short* src = xb + (size_t)(l0 + srow) * CIN + c0 + schunk * 8;
#pragma unroll
    for (int rd = 0; rd < 4; ++rd)
      gl2lds16(&Bs[buf][0] + lds_off + rd * 2048, src + (size_t)rd * 32 * CIN);
    if (t < 64) {
      const int r2  = 128 + (t >> 3);
      const int ch2 = (t & 7) ^ (r2 & 7);
      gl2lds16(&Bs[buf][0] + 128 * 64 + t * 8,
               xb + (size_t)(l0 + r2) * CIN + c0 + ch2 * 8);
    }
  };

  stage_B(0, 0);
  stage_A(0, 0);
  __syncthreads();

#pragma unroll 1
  for (int kk = 0; kk < 64; ++kk) {
    const int k  = kk & 7;
    const int ct = kk >> 3;
    // issue next-phase staging FIRST (in flight across this tap's compute)
    if (kk + 1 < 64) stage_A(kk + 1, (kk + 1) & 1);
    if (k == 7 && ct + 1 < 8) stage_B(ct + 1, (ct + 1) & 1);

    const unsigned short* Ac = &As[kk & 1][0];
    const unsigned short* Bc = &Bs[ct & 1][0];
#pragma unroll
    for (int h = 0; h < 2; ++h) {
      bf16x8_t af[4], bfr[4];
#pragma unroll
      for (int i = 0; i < 4; ++i) {
        int row  = wm * 64 + i * 16 + lrow;
        int slot = (h * 4 + quad) ^ (row & 7);
        af[i] = *(const bf16x8_t*)(Ac + row * 64 + slot * 8);
      }
#pragma unroll
      for (int j = 0; j < 4; ++j) {
        int row  = (8 - k) + wn * 64 + j * 16 + lrow;   // halo shift
        int slot = (h * 4 + quad) ^ (row & 7);
        bfr[j] = *(const bf16x8_t*)(Bc + row * 64 + slot * 8);
      }
#pragma unroll
      for (int i = 0; i < 4; ++i)
#pragma unroll
        for (int j = 0; j < 4; ++j)
          acc[i][j] = __builtin_amdgcn_mfma_f32_16x16x32_bf16(af[i], bfr[j], acc[i][j], 0, 0, 0);
    }
    __syncthreads();  // single barrier: guards buffer swap; vmcnt drain ~free
  }

  // epilogue: D layout col = lane&15 (=l), row = quad*4+reg (=o)
#pragma unroll
  for (int i = 0; i < 4; ++i) {
    const int o_base = o0 + wm * 64 + i * 16 + quad * 4;
    const float4 bv = *(const float4*)(bias + o_base);
    const float bvr[4] = {bv.x, bv.y, bv.z, bv.w};
#pragma unroll
    for (int j = 0; j < 4; ++j) {
      const int l = l0 + wn * 64 + j * 16 + lrow;
#pragma unroll
      for (int r = 0; r < 4; ++r) {
        y[((size_t)b * COUT + o_base + r) * LLEN + l] = acc[i][j][r] + bvr[r];
      }
    }
  }
}

// ---------------- launch ----------------

extern "C" void kernel_launch(void* const* d_in, const int* in_sizes, int n_in,
                              void* d_out, int out_size, void* d_ws, size_t ws_size,
                              hipStream_t stream) {
  const float* x    = (const float*)d_in[0];   // (8, 512, 2048)
  const float* W    = (const float*)d_in[1];   // (4096, 512)
  const float* bias = (const float*)d_in[2];   // (512)
  float* y          = (float*)d_out;           // (8, 512, 2048)

  unsigned short* xtp = (unsigned short*)d_ws;                     // 16,842,752 B
  unsigned short* Wb  = (unsigned short*)((char*)d_ws +
                        (size_t)BATCH * LPAD * CIN * sizeof(unsigned short));

  prepass_kernel<<<2048 + 1024, 256, 0, stream>>>(
      x, xtp, (const float4*)W, (u16x8_t*)Wb);
  conv_gemm_kernel<<<dim3(LLEN / 128, COUT / 128, BATCH), 256, 0, stream>>>(
      Wb, xtp, bias, y);
}